// Round 1
// baseline (730.672 us; speedup 1.0000x reference)
//
#include <hip/hip_runtime.h>

typedef unsigned short u16;
typedef unsigned int u32;
typedef __attribute__((ext_vector_type(8))) short bf16x8;
typedef __attribute__((ext_vector_type(4))) float f32x4;

__device__ __forceinline__ u16 f2bf(float f) {
  u32 u = __float_as_uint(f);
  u32 r = (u + 0x7FFFu + ((u >> 16) & 1u)) >> 16;  // RTNE
  return (u16)r;
}

__device__ __forceinline__ void gl_lds16(const u16* g, u16* l) {
  __builtin_amdgcn_global_load_lds(
      (const __attribute__((address_space(1))) u32*)g,
      (__attribute__((address_space(3))) u32*)l, 16, 0, 0);
}

// ---------------- prep: U fp32 -> bf16 ----------------
__global__ __launch_bounds__(256) void cvt_bf16(const float* __restrict__ src,
                                                u16* __restrict__ dst, int n4) {
  int g = blockIdx.x * 256 + threadIdx.x;
  if (g < n4) {
    float4 v = ((const float4*)src)[g];
    ushort4 o;
    o.x = f2bf(v.x); o.y = f2bf(v.y); o.z = f2bf(v.z); o.w = f2bf(v.w);
    ((ushort4*)dst)[g] = o;
  }
}

// ---------------- prep: x fp32 -> Xb bf16 [b][l][d] and XT bf16 [b][d][l] ----------------
__global__ __launch_bounds__(256) void prep_x(const float* __restrict__ x,
                                              u16* __restrict__ Xb,
                                              u16* __restrict__ XT) {
  __shared__ u16 t[32][33];
  const int b = blockIdx.z;
  const int l0 = blockIdx.y * 32;
  const int d0 = blockIdx.x * 32;
  const int j = threadIdx.x & 31;
  const int t5 = threadIdx.x >> 5;
#pragma unroll
  for (int r = 0; r < 4; r++) {
    int i = r * 8 + t5;
    float v = x[((size_t)b * 2048 + l0 + i) * 512 + d0 + j];
    u16 h = f2bf(v);
    t[i][j] = h;
    Xb[((size_t)b * 2048 + l0 + i) * 512 + d0 + j] = h;
  }
  __syncthreads();
#pragma unroll
  for (int r = 0; r < 4; r++) {
    int i = r * 8 + t5;
    XT[((size_t)b * 512 + d0 + i) * 2048 + l0 + j] = t[j][i];
  }
}

// ---------------- rz[row] = 1 / sum_l P[row][l] ----------------
__global__ __launch_bounds__(256) void zsum(const u16* __restrict__ P,
                                            float* __restrict__ rz) {
  const int row = blockIdx.x * 4 + (threadIdx.x >> 6);
  const int lane = threadIdx.x & 63;
  const uint4* pr = (const uint4*)(P + (size_t)row * 2048);
  float s = 0.f;
#pragma unroll
  for (int k2 = 0; k2 < 4; k2++) {
    uint4 v = pr[lane + k2 * 64];
    u32 u0 = v.x, u1 = v.y, u2 = v.z, u3 = v.w;
    s += __uint_as_float(u0 << 16) + __uint_as_float(u0 & 0xffff0000u);
    s += __uint_as_float(u1 << 16) + __uint_as_float(u1 & 0xffff0000u);
    s += __uint_as_float(u2 << 16) + __uint_as_float(u2 & 0xffff0000u);
    s += __uint_as_float(u3 << 16) + __uint_as_float(u3 & 0xffff0000u);
  }
#pragma unroll
  for (int off = 32; off > 0; off >>= 1) s += __shfl_down(s, off);
  if (lane == 0) rz[row] = 1.f / s;
}

// ---------------- GEMM: C = A[M][K] @ B[N][K]^T, m97-style 128x128 tile ----------------
// EPI=0: out = bf16(exp(acc)) -> u16*, stride N
// EPI=1: out = acc * rz[row]  -> float*, stride N
template <int EPI>
__global__ __launch_bounds__(256)
void gemm_bt(const u16* __restrict__ A, const u16* __restrict__ B,
             void* __restrict__ Cout, const float* __restrict__ rz,
             int K, int N) {
  __shared__ u16 lA[128 * 32];
  __shared__ u16 lB[128 * 32];
  __shared__ float rz_lds[128];
  const int tid = threadIdx.x;
  const int lane = tid & 63;
  const int wv = tid >> 6;            // wave 0..3
  const int m0 = blockIdx.y * 128;
  const int n0 = blockIdx.x * 128;
  if (EPI == 1 && tid < 128) rz_lds[tid] = rz[m0 + tid];
  const int wy = wv >> 1, wx = wv & 1;  // 2x2 wave grid, 64x64 per wave
  const int sr = lane >> 2;             // staging row in 16-row chunk
  const int sc = (lane & 3) * 8;        // staging k offset (elems)
  const int fr = lane & 15;             // fragment row/col
  const int fo = (lane >> 4) * 8;       // fragment k offset

  f32x4 acc[4][4] = {};
  const u16* Ab = A + (size_t)(m0 + wv * 32 + sr) * K + sc;
  const u16* Bb = B + (size_t)(n0 + wv * 32 + sr) * K + sc;
  const size_t rowskip = (size_t)16 * K;

  for (int k0 = 0; k0 < K; k0 += 32) {
    gl_lds16(Ab + k0,           &lA[(wv * 2 + 0) * 512]);
    gl_lds16(Ab + k0 + rowskip, &lA[(wv * 2 + 1) * 512]);
    gl_lds16(Bb + k0,           &lB[(wv * 2 + 0) * 512]);
    gl_lds16(Bb + k0 + rowskip, &lB[(wv * 2 + 1) * 512]);
    __syncthreads();
    bf16x8 af[4], bfr[4];
#pragma unroll
    for (int t = 0; t < 4; t++) {
      af[t]  = *(const bf16x8*)&lA[(wy * 64 + t * 16 + fr) * 32 + fo];
      bfr[t] = *(const bf16x8*)&lB[(wx * 64 + t * 16 + fr) * 32 + fo];
    }
#pragma unroll
    for (int yb = 0; yb < 4; yb++)
#pragma unroll
      for (int xb = 0; xb < 4; xb++)
        acc[yb][xb] = __builtin_amdgcn_mfma_f32_16x16x32_bf16(
            af[yb], bfr[xb], acc[yb][xb], 0, 0, 0);
    __syncthreads();
  }

#pragma unroll
  for (int yb = 0; yb < 4; yb++) {
#pragma unroll
    for (int xb = 0; xb < 4; xb++) {
      const int rl = wy * 64 + yb * 16 + (lane >> 4) * 4;  // local row (0..127)
      const int col = n0 + wx * 64 + xb * 16 + fr;
#pragma unroll
      for (int r = 0; r < 4; r++) {
        if (EPI == 0) {
          ((u16*)Cout)[(size_t)(m0 + rl + r) * N + col] = f2bf(__expf(acc[yb][xb][r]));
        } else {
          ((float*)Cout)[(size_t)(m0 + rl + r) * N + col] = acc[yb][xb][r] * rz_lds[rl + r];
        }
      }
    }
  }
}

// B=8, L=2048, D=512, Y=8192
extern "C" void kernel_launch(void* const* d_in, const int* in_sizes, int n_in,
                              void* d_out, int out_size, void* d_ws, size_t ws_size,
                              hipStream_t stream) {
  const float* x = (const float*)d_in[0];   // [8][2048][512]
  const float* U = (const float*)d_in[1];   // [8192][512]
  if (n_in >= 2 && in_sizes[0] == 8192 * 512) {  // guard against input order swap
    x = (const float*)d_in[1];
    U = (const float*)d_in[0];
  }
  float* out = (float*)d_out;               // [8][8192][512]
  char* ws = (char*)d_ws;

  // ws layout
  u16* Ub = (u16*)ws;                                   // 8192*512*2   = 8 MiB
  u16* Xb = (u16*)(ws + 8388608);                       // 8*2048*512*2 = 16 MiB
  u16* XT = (u16*)(ws + 8388608 + 16777216);            // 16 MiB
  u16* P  = (u16*)(ws + 8388608 + 2 * 16777216);        // 8192*2048*2  = 32 MiB
  float* rz = (float*)(ws + 8388608 + 2 * 16777216 + 33554432);  // 32 KiB

  cvt_bf16<<<4096, 256, 0, stream>>>(U, Ub, (8192 * 512) / 4);
  prep_x<<<dim3(16, 64, 8), 256, 0, stream>>>(x, Xb, XT);

  for (int b = 0; b < 8; b++) {
    // P = exp(U @ x_b^T): M=8192, N=2048, K=512
    gemm_bt<0><<<dim3(16, 64), 256, 0, stream>>>(
        Ub, Xb + (size_t)b * 2048 * 512, P, nullptr, 512, 2048);
    // rz = 1 / rowsum(P)
    zsum<<<2048, 256, 0, stream>>>(P, rz);
    // out_b = (P @ x_b) * rz: M=8192, N=512, K=2048
    gemm_bt<1><<<dim3(4, 64), 256, 0, stream>>>(
        P, XT + (size_t)b * 512 * 2048, out + (size_t)b * 8192 * 512, rz, 2048, 512);
  }
}